// Round 1
// baseline (79.292 us; speedup 1.0000x reference)
//
#include <hip/hip_runtime.h>

#define FSC 256
#define HH 256
#define WW 256
#define CC 64
#define NG 8
#define NE 32
#define THRESH 15.0f

// feats: (8,256,256,65) floats, then mask: (8,256,256) floats
#define FEATS_ELEMS ((size_t)NG * HH * WW * 65)

__global__ __launch_bounds__(256) void fused_sparse_encoder(
    const float* __restrict__ img,    // (64,256,256)
    const float* __restrict__ edges,  // (8,32,4)
    float* __restrict__ out)
{
#pragma clang fp contract(off)
    // LDS
    __shared__ float s_img[130 * 65];          // [(yy*65+x)][c], 33.8 KB
    __shared__ float s_e0v[NG * NE], s_e0u[NG * NE];
    __shared__ float s_e1v[NG * NE], s_e1u[NG * NE];
    __shared__ float s_dn0[NG * NE], s_dn1[NG * NE], s_Lm[NG * NE];
    __shared__ float s_mask[NG * 64];
    __shared__ float s_pinfo[NG * 64];

    const int tid = threadIdx.x;
    const int u0  = blockIdx.x * 64;
    const int v   = blockIdx.y;

    // ---- Phase A: per-edge precompute (256 threads = 8 groups x 32 edges)
    {
        const float4 e4 = reinterpret_cast<const float4*>(edges)[tid];
        float e0v = e4.x * 256.0f;
        float e0u = e4.y * 256.0f;
        float e1v = e4.z * 256.0f;
        float e1u = e4.w * 256.0f;
        float d0 = e1v - e0v;
        float d1 = e1u - e0u;
        float L  = __fsqrt_rn(d0 * d0 + d1 * d1);
        float Lm = fmaxf(L, 1e-4f);
        s_e0v[tid] = e0v; s_e0u[tid] = e0u;
        s_e1v[tid] = e1v; s_e1u[tid] = e1u;
        s_dn0[tid] = __fdiv_rn(d0, Lm);
        s_dn1[tid] = __fdiv_rn(d1, Lm);
        s_Lm[tid]  = Lm;
    }
    __syncthreads();

    // ---- Phase B: mask + pinfo for (g, px). 512 combos / 256 threads = 2 each.
    {
        const int px = tid & 63;
        const float U = (float)(u0 + px);
        const float V = (float)v;
        for (int half = 0; half < 2; ++half) {
            const int g = (tid >> 6) + half * 4;
            float sm = 0.0f, cnt = 0.0f;
            bool any = false;
            for (int e = 0; e < NE; ++e) {
                const int idx = g * NE + e;
                const float diff0 = V - s_e0v[idx];
                const float diff1 = U - s_e0u[idx];
                const float dn0 = s_dn0[idx];
                const float dn1 = s_dn1[idx];
                const float nd = fabsf(diff0 * dn1 + diff1 * (-dn0));
                const float dd = __fdiv_rn(diff0 * dn0 + diff1 * dn1, s_Lm[idx]);
                const float r0 = __fsqrt_rn(diff0 * diff0 + diff1 * diff1);
                const float f0 = V - s_e1v[idx];
                const float f1 = U - s_e1u[idx];
                const float r1 = __fsqrt_rn(f0 * f0 + f1 * f1);
                const bool m = ((nd <= THRESH) && (dd <= 1.0f) && (dd >= 0.0f))
                               || (r0 <= THRESH) || (r1 <= THRESH);
                if (m) {
                    any = true;
                    sm += fminf(dd, 1.0f - dd);
                    cnt += 1.0f;
                }
            }
            const float pf = __fdiv_rn(sm, fmaxf(cnt, 1e-4f));
            const float mv = any ? 1.0f : 0.0f;
            s_mask[g * 64 + px]  = mv;
            s_pinfo[g * 64 + px] = pf;
            out[FEATS_ELEMS + ((size_t)g * HH + v) * WW + (u0 + px)] = mv;
        }
    }

    // ---- Phase C: stage image tile: rows {v-1, v}, cols {u0-1 .. u0+63}, 64 ch.
    // linear i = (c*2 + yy)*65 + x, total 8320 elements.
    {
        for (int i = tid; i < CC * 2 * 65; i += 256) {
            const int c  = i / 130;
            const int r  = i - c * 130;
            const int yy = r / 65;
            const int x  = r - yy * 65;
            const int gy = v - 1 + yy;
            const int gx = u0 - 1 + x;
            float val = 0.0f;
            if (gy >= 0 && gx >= 0) {   // gy<=v<=255, gx<=u0+63<=255 always
                val = img[((size_t)c * HH + gy) * WW + gx];
            }
            s_img[(yy * 65 + x) * 65 + c] = val;
        }
    }
    __syncthreads();

    // ---- Phase D: sample + broadcast-masked write. Wave w owns pixels [16w,16w+16).
    {
        const int wv = tid >> 6;
        const int lane = tid & 63;
        for (int p = wv * 16; p < wv * 16 + 16; ++p) {
            // x0 = local col p (= global u-1), x1 = p+1 (= global u); yy0 = v-1, yy1 = v
            const float s = s_img[(p) * 65 + lane] * 0.25f
                          + s_img[(p + 1) * 65 + lane] * 0.25f
                          + s_img[(65 + p) * 65 + lane] * 0.25f
                          + s_img[(66 + p) * 65 + lane] * 0.25f;
            const int u = u0 + p;
            for (int g = 0; g < NG; ++g) {
                const float m = s_mask[g * 64 + p];
                const size_t base = (((size_t)g * HH + v) * WW + u) * 65;
                out[base + lane] = s * m;
                if (lane == 0) {
                    out[base + 64] = s_pinfo[g * 64 + p] * m;
                }
            }
        }
    }
}

extern "C" void kernel_launch(void* const* d_in, const int* in_sizes, int n_in,
                              void* d_out, int out_size, void* d_ws, size_t ws_size,
                              hipStream_t stream) {
    const float* img   = (const float*)d_in[0];
    const float* edges = (const float*)d_in[1];
    float* out = (float*)d_out;
    dim3 grid(WW / 64, HH);
    fused_sparse_encoder<<<grid, 256, 0, stream>>>(img, edges, out);
}

// Round 2
// 66.583 us; speedup vs baseline: 1.1909x; 1.1909x over previous
//
#include <hip/hip_runtime.h>

#define HH 256
#define WW 256
#define CC 64
#define NG 8
#define NE 32
#define THRESH 15.0f

// out layout: feats (8,256,256,65) floats, then mask (8,256,256) floats
#define FEATS_ELEMS ((size_t)NG * HH * WW * 65)

__global__ __launch_bounds__(256) void fused_sparse_encoder(
    const float* __restrict__ img,    // (64,256,256)
    const float* __restrict__ edges,  // (8,32,4)
    float* __restrict__ out)
{
#pragma clang fp contract(off)
    // s_buf dual use:
    //   Phase C/D1: image tile  [(yy*65 + x)*65 + c], 130*65 = 8450 floats
    //   Phase D2/E: t tile      [p*65 + cell], first 64*65 = 4160 floats
    __shared__ float s_buf[130 * 65];
    __shared__ float s_e0v[NG * NE], s_e0u[NG * NE];
    __shared__ float s_e1v[NG * NE], s_e1u[NG * NE];
    __shared__ float s_dn0[NG * NE], s_dn1[NG * NE], s_Lm[NG * NE];
    __shared__ float s_mask[NG * 64];
    __shared__ float s_pinfo[NG * 64];

    const int tid = threadIdx.x;
    const int u0  = blockIdx.x * 64;
    const int v   = blockIdx.y;

    // ---- Phase A: per-edge precompute (256 threads = 8 groups x 32 edges)
    {
        const float4 e4 = reinterpret_cast<const float4*>(edges)[tid];
        float e0v = e4.x * 256.0f;
        float e0u = e4.y * 256.0f;
        float e1v = e4.z * 256.0f;
        float e1u = e4.w * 256.0f;
        float d0 = e1v - e0v;
        float d1 = e1u - e0u;
        float L  = __fsqrt_rn(d0 * d0 + d1 * d1);
        float Lm = fmaxf(L, 1e-4f);
        s_e0v[tid] = e0v; s_e0u[tid] = e0u;
        s_e1v[tid] = e1v; s_e1u[tid] = e1u;
        s_dn0[tid] = __fdiv_rn(d0, Lm);
        s_dn1[tid] = __fdiv_rn(d1, Lm);
        s_Lm[tid]  = Lm;
    }
    __syncthreads();

    // ---- Phase B: mask + pinfo for (g, px). 512 combos / 256 threads = 2 each.
    {
        const int px = tid & 63;
        const float U = (float)(u0 + px);
        const float V = (float)v;
        for (int half = 0; half < 2; ++half) {
            const int g = (tid >> 6) + half * 4;
            float sm = 0.0f, cnt = 0.0f;
            bool any = false;
            for (int e = 0; e < NE; ++e) {
                const int idx = g * NE + e;
                const float diff0 = V - s_e0v[idx];
                const float diff1 = U - s_e0u[idx];
                const float dn0 = s_dn0[idx];
                const float dn1 = s_dn1[idx];
                const float nd = fabsf(diff0 * dn1 + diff1 * (-dn0));
                const float dd = __fdiv_rn(diff0 * dn0 + diff1 * dn1, s_Lm[idx]);
                const float r0 = __fsqrt_rn(diff0 * diff0 + diff1 * diff1);
                const float f0 = V - s_e1v[idx];
                const float f1 = U - s_e1u[idx];
                const float r1 = __fsqrt_rn(f0 * f0 + f1 * f1);
                const bool m = ((nd <= THRESH) && (dd <= 1.0f) && (dd >= 0.0f))
                               || (r0 <= THRESH) || (r1 <= THRESH);
                if (m) {
                    any = true;
                    sm += fminf(dd, 1.0f - dd);
                    cnt += 1.0f;
                }
            }
            const float pf = __fdiv_rn(sm, fmaxf(cnt, 1e-4f));
            const float mv = any ? 1.0f : 0.0f;
            s_mask[g * 64 + px]  = mv;
            s_pinfo[g * 64 + px] = pf;
            out[FEATS_ELEMS + ((size_t)g * HH + v) * WW + (u0 + px)] = mv;
        }
    }

    // ---- Phase C: stage image tile: rows {v-1, v}, cols {u0-1 .. u0+63}, 64 ch.
    {
        for (int i = tid; i < CC * 2 * 65; i += 256) {
            const int c  = i / 130;
            const int r  = i - c * 130;
            const int yy = r / 65;
            const int x  = r - yy * 65;
            const int gy = v - 1 + yy;
            const int gx = u0 - 1 + x;
            float val = 0.0f;
            if (gy >= 0 && gx >= 0) {   // gy<=v<=255, gx<=u0+63<=255 always
                val = img[((size_t)c * HH + gy) * WW + gx];
            }
            s_buf[(yy * 65 + x) * 65 + c] = val;
        }
    }
    __syncthreads();

    // ---- Phase D1: sample into registers. Wave wv owns pixels [16*wv, 16*wv+16); lane = channel.
    const int wv   = tid >> 6;
    const int lane = tid & 63;
    float sreg[16];
    #pragma unroll
    for (int i = 0; i < 16; ++i) {
        const int p = wv * 16 + i;
        sreg[i] = s_buf[(p) * 65 + lane] * 0.25f
                + s_buf[(p + 1) * 65 + lane] * 0.25f
                + s_buf[(65 + p) * 65 + lane] * 0.25f
                + s_buf[(66 + p) * 65 + lane] * 0.25f;
    }
    __syncthreads();

    // ---- Phase D2: transpose to t tile: t[p*65 + c] = s  (aliases s_buf)
    #pragma unroll
    for (int i = 0; i < 16; ++i) {
        const int p = wv * 16 + i;
        s_buf[p * 65 + lane] = sreg[i];
    }
    __syncthreads();

    // ---- Phase E: per g, stream out 4160 floats (1040 float4) fully aligned+contiguous.
    for (int g = 0; g < NG; ++g) {
        const float* msk = &s_mask[g * 64];
        const float* pin = &s_pinfo[g * 64];
        float* gout = out + (((size_t)g * HH + v) * WW + u0) * 65;
        #pragma unroll
        for (int k = 0; k < 5; ++k) {
            const int q = tid + k * 256;
            if (q < 1040) {
                const int f  = q * 4;
                const int p0 = (int)((unsigned)f / 65u);          // magic-mul div
                const int b  = (p0 + 1) * 65 - f;                 // elems e<b belong to p0
                const float4 tv = *reinterpret_cast<const float4*>(&s_buf[f]);
                const float m0  = msk[p0];
                const float m1  = msk[(b < 4) ? (p0 + 1) : p0];
                const float pi0 = pin[p0];
                float r0 = ((b == 1) ? pi0 : tv.x) * ((0 < b) ? m0 : m1);
                float r1 = ((b == 2) ? pi0 : tv.y) * ((1 < b) ? m0 : m1);
                float r2 = ((b == 3) ? pi0 : tv.z) * ((2 < b) ? m0 : m1);
                float r3 = ((b == 4) ? pi0 : tv.w) * ((3 < b) ? m0 : m1);
                *reinterpret_cast<float4*>(&gout[f]) = make_float4(r0, r1, r2, r3);
            }
        }
    }
}

extern "C" void kernel_launch(void* const* d_in, const int* in_sizes, int n_in,
                              void* d_out, int out_size, void* d_ws, size_t ws_size,
                              hipStream_t stream) {
    const float* img   = (const float*)d_in[0];
    const float* edges = (const float*)d_in[1];
    float* out = (float*)d_out;
    dim3 grid(WW / 64, HH);
    fused_sparse_encoder<<<grid, 256, 0, stream>>>(img, edges, out);
}